// Round 1
// baseline (892.634 us; speedup 1.0000x reference)
//
#include <hip/hip_runtime.h>

// HBV 2.0 fused scan + gamma-UH routing, MI355X (gfx950).
// T=730, G=10000, NMUL=2. 20,000 independent serial chains -> latency-bound.
// thread = (g, m): lanes 0..31 handle m=0, lanes 32..63 handle m=1 of the
// same 32 grid cells. Qsim mean via __shfl_xor(Q,32). Routing fused via a
// 15-deep static ring accumulator (time unrolled in chunks of LENF=15).
// Input chunks double-buffered in registers to hide ~900cy HBM latency at
// ~1 wave/SIMD occupancy.

#define TS 730
#define NG 10000
#define CH 15
#define NPAIR 25  // 50 chunks of 15 = 750 steps (clamped/masked past 729)

struct F3 { float x, y, z; };  // 4-byte-aligned 12B load (NOT float3/ext_vector)

__global__ __launch_bounds__(64, 1) void hbv_fused(
    const float* __restrict__ x_phy,
    const float* __restrict__ ac_all,
    const float* __restrict__ params_dy,
    const float* __restrict__ params_stat,
    float* __restrict__ out)
{
    const int lane = threadIdx.x & 63;
    const int m    = lane >> 5;            // nmul component
    const int g    = blockIdx.x * 32 + (lane & 31);
    const int gl   = g < NG ? g : NG - 1;  // clamped for loads; stores masked

    // ---- static params: params_stat[g, i*2 + m], i=0..13; rout at 28,29 ----
    const float* ps = params_stat + gl * 30;
    const float FC    = ps[0  + m] * 950.f   + 50.f;
    const float K0    = ps[2  + m] * 0.85f   + 0.05f;
    const float K1    = ps[4  + m] * 0.49f   + 0.01f;
    const float K2    = ps[6  + m] * 0.199f  + 0.001f;
    const float LP    = ps[8  + m] * 0.8f    + 0.2f;
    const float PERCp = ps[10 + m] * 10.f;
    const float UZL   = ps[12 + m] * 100.f;
    const float TTp   = ps[14 + m] * 5.f     - 2.5f;
    const float CFMAX = ps[16 + m] * 9.5f    + 0.5f;
    const float CFR   = ps[18 + m] * 0.1f;
    const float CWH   = ps[20 + m] * 0.2f;
    const float Cc    = ps[22 + m];               // bounds (0,1)
    const float RT    = ps[24 + m] * 20.f;
    const float ACp   = ps[26 + m] * 2500.f;
    const float ra    = ps[28] * 2.9f;
    const float rb    = ps[29] * 6.5f;

    const float Acv     = ac_all[gl];
    const float invFC   = 1.f / FC;
    const float invLPFC = 1.f / (LP * FC);
    const float CFRC    = CFR * CFMAX;
    // parRT * clip(1 - Ac/(AC+eps), 0, 1): constant per thread
    const float gwcap = RT * fminf(fmaxf(1.f - Acv / (ACp + 1e-5f), 0.f), 1.f);

    // ---- UH weights: normalization cancels exp(-gammaln(a))*theta^-a ----
    const float a     = fmaxf(ra, 0.f) + 0.1f;   // [0.1, 3.0]
    const float th    = fmaxf(rb, 0.f) + 0.5f;   // [0.5, 7.0]
    const float am1   = a - 1.f;
    const float invth = 1.f / th;
    float w[CH];
    float wsum = 0.f;
#pragma unroll
    for (int k = 0; k < CH; ++k) {
        const float tk = (float)k + 0.5f;
        const float v  = __powf(tk, am1) * __expf(-tk * invth);
        w[k] = v; wsum += v;
    }
    const float wn = 0.5f / wsum;  // fold nmul-mean 0.5 into weights
#pragma unroll
    for (int k = 0; k < CH; ++k) w[k] *= wn;

    // ---- state + routing ring accumulator ----
    float SP = 1e-3f, MW = 1e-3f, SM = 1e-3f, SUZ = 1e-3f, SLZ = 1e-3f;
    float facc[CH];
#pragma unroll
    for (int k = 0; k < CH; ++k) facc[k] = 0.f;

    // ---- double-buffered 15-step input blocks ----
    float Ap[CH], At[CH], Ae[CH], Ab[CH], Abe[CH];
    float Bp[CH], Bt[CH], Be[CH], Bb[CH], Bbe[CH];

    auto loadCh = [&](int c, float* P, float* Ta, float* E, float* Bq, float* BE) {
#pragma unroll
        for (int j = 0; j < CH; ++j) {
            int t = c * CH + j;
            t = t < TS ? t : TS - 1;                 // clamp tail (stores masked)
            const size_t o = (size_t)t * NG + gl;
            const F3 xv = *(const F3*)(x_phy + 3 * o);
            P[j] = xv.x; Ta[j] = xv.y; E[j] = xv.z;
            const float* dp = params_dy + 4 * o;     // [beta0,beta1,betaet0,betaet1]
            Bq[j] = dp[m];
            BE[j] = dp[2 + m];
        }
    };

    auto compCh = [&](int c, const float* P, const float* Ta, const float* E,
                      const float* Bq, const float* BE) {
#pragma unroll
        for (int j = 0; j < CH; ++j) {
            const float Pt = P[j], Tt = Ta[j], PETt = E[j];
            const float beta   = Bq[j] * 5.f  + 1.f;
            const float betaet = BE[j] * 4.7f + 0.3f;

            // snow bucket
            const float rain = (Tt >= TTp) ? Pt : 0.f;
            const float snow = Pt - rain;
            SP += snow;
            const float melt = fminf(fmaxf(CFMAX * (Tt - TTp), 0.f), SP);
            MW += melt; SP -= melt;
            const float refr = fminf(fmaxf(CFRC * (TTp - Tt), 0.f), MW);
            SP += refr; MW -= refr;
            const float tosoil = fmaxf(MW - CWH * SP, 0.f);
            MW -= tosoil;

            // soil bucket (SM > 0 always -> pow via native log/exp is safe)
            const float sw   = fminf(__powf(SM * invFC, beta), 1.f);
            const float rts  = rain + tosoil;
            const float rech = rts * sw;
            SM += rts - rech;
            const float exc = fmaxf(SM - FC, 0.f);
            SM -= exc;
            const float ef = __powf(fminf(SM * invLPFC, 1.f), betaet);
            const float ET = fminf(SM, PETt * ef);
            SM = fmaxf(SM - ET, 1e-5f);
            const float cap = fminf(SLZ, Cc * SLZ * (1.f - fminf(SM * invFC, 1.f)));
            SM  = fmaxf(SM + cap, 1e-5f);
            SLZ = fmaxf(SLZ - cap, 1e-5f);

            // groundwater buckets
            SUZ += rech + exc;
            const float perc = fminf(SUZ, PERCp);
            SUZ -= perc;
            const float Q0 = K0 * fmaxf(SUZ - UZL, 0.f);
            SUZ -= Q0;
            const float Q1 = K1 * SUZ;
            SUZ -= Q1;
            SLZ += perc;
            const float gw = fminf(SLZ, gwcap);
            SLZ -= gw;
            const float Q2 = K2 * SLZ;
            SLZ -= Q2;
            const float Qt = Q0 + Q1 + Q2;

            // nmul mean (0.5 folded into w) + fused causal UH conv:
            // Q at time t contributes w[k] to flow[t+k]; ring phase = t%15 = j.
            const float Qc = Qt + __shfl_xor(Qt, 32);
#pragma unroll
            for (int k = 0; k < CH; ++k)
                facc[(j + k) % CH] = fmaf(w[k], Qc, facc[(j + k) % CH]);

            const int t = c * CH + j;
            if (lane < 32 && g < NG && t < TS)
                out[(size_t)t * NG + g] = facc[j];  // flow[t] now complete
            facc[j] = 0.f;                          // recycle slot for t+15
        }
    };

    loadCh(0, Ap, At, Ae, Ab, Abe);
    for (int it = 0; it < NPAIR; ++it) {
        const int c0 = 2 * it;
        loadCh(c0 + 1, Bp, Bt, Be, Bb, Bbe);   // prefetch next chunk
        compCh(c0,     Ap, At, Ae, Ab, Abe);   // compute current
        loadCh(c0 + 2, Ap, At, Ae, Ab, Abe);   // (clamped at the tail)
        compCh(c0 + 1, Bp, Bt, Be, Bb, Bbe);
    }
}

extern "C" void kernel_launch(void* const* d_in, const int* in_sizes, int n_in,
                              void* d_out, int out_size, void* d_ws, size_t ws_size,
                              hipStream_t stream) {
    const float* x_phy = (const float*)d_in[0];
    const float* ac    = (const float*)d_in[1];
    // d_in[2] = elev_all: unused by the reference forward
    const float* pdy   = (const float*)d_in[3];
    const float* pst   = (const float*)d_in[4];
    float* out = (float*)d_out;

    const int grid = (NG + 31) / 32;  // 313 blocks x 1 wave -> spread over CUs
    hbv_fused<<<grid, 64, 0, stream>>>(x_phy, ac, pdy, pst, out);
}

// Round 2
// 872.668 us; speedup vs baseline: 1.0229x; 1.0229x over previous
//
#include <hip/hip_runtime.h>

// HBV 2.0 fused scan + gamma-UH routing, MI355X (gfx950). Round 2.
// 20,000 independent serial chains (G=10000 x NMUL=2) -> latency-bound.
// R1 failure: register double-buffer spilled (VGPR=124 < ~180 live) and the
// per-step out-store + facc rewrite forced s_waitcnt vmcnt(0) every step,
// draining the prefetch queue (2450 cyc/step). R2: compute loop has ZERO
// VMEM ops -- inputs staged global->reg->LDS one chunk ahead (vmcnt only at
// the per-chunk ds_write), compute reads LDS (lgkmcnt), outputs buffered in
// regs and stored once per chunk.

#define TS 730
#define NG 10000
#define CH 15
#define NCHUNK 49  // 49*15 = 735 >= 730; tail loads clamped, stores masked

__global__ __launch_bounds__(64, 1) void hbv_fused(
    const float* __restrict__ x_phy,
    const float* __restrict__ ac_all,
    const float* __restrict__ params_dy,
    const float* __restrict__ params_stat,
    float* __restrict__ out)
{
    // LDS double buffers. xb: straight copy [j][cell][3] (stride-3 reads:
    // conflict-free). db: 4 planes [beta_m0, beta_m1, betaet_m0, betaet_m1]
    // x [j][cell] (stride-1 reads: conflict-free, 2-way across halves = free).
    __shared__ float xb[2][CH * 32 * 3];
    __shared__ float db[2][4][CH * 32];

    const int lane = threadIdx.x & 63;
    const int m    = lane >> 5;            // nmul component
    const int cell = lane & 31;
    const int g0   = blockIdx.x * 32;
    const int g    = g0 + cell;
    const int gl   = g < NG ? g : NG - 1;
    // last block: shift the 32-cell load window left so staging never reads OOB
    const int g0r  = (g0 <= NG - 32) ? g0 : NG - 32;
    const int co   = cell + (g0 - g0r);
    const int cl   = co < 31 ? co : 31;    // LDS cell slot for this thread

    // ---- static params: params_stat[g, i*2 + m]; routing at 28,29 ----
    const float* ps = params_stat + (size_t)gl * 30;
    const float FC    = ps[0  + m] * 950.f   + 50.f;
    const float K0    = ps[2  + m] * 0.85f   + 0.05f;
    const float K1    = ps[4  + m] * 0.49f   + 0.01f;
    const float K2    = ps[6  + m] * 0.199f  + 0.001f;
    const float LP    = ps[8  + m] * 0.8f    + 0.2f;
    const float PERCp = ps[10 + m] * 10.f;
    const float UZL   = ps[12 + m] * 100.f;
    const float TTp   = ps[14 + m] * 5.f     - 2.5f;
    const float CFMAX = ps[16 + m] * 9.5f    + 0.5f;
    const float CFR   = ps[18 + m] * 0.1f;
    const float CWH   = ps[20 + m] * 0.2f;
    const float Cc    = ps[22 + m];
    const float RT    = ps[24 + m] * 20.f;
    const float ACp   = ps[26 + m] * 2500.f;
    const float ra    = ps[28] * 2.9f;
    const float rb    = ps[29] * 6.5f;

    const float Acv     = ac_all[gl];
    const float invFC   = 1.f / FC;
    const float invLPFC = 1.f / (LP * FC);
    const float CFRC    = CFR * CFMAX;
    const float gwcap   = RT * fminf(fmaxf(1.f - Acv / (ACp + 1e-5f), 0.f), 1.f);

    // ---- UH weights (normalization cancels gammaln/theta^-a prefactor) ----
    const float a     = fmaxf(ra, 0.f) + 0.1f;
    const float th    = fmaxf(rb, 0.f) + 0.5f;
    const float am1   = a - 1.f;
    const float invth = 1.f / th;
    float w[CH];
    float wsum = 0.f;
#pragma unroll
    for (int k = 0; k < CH; ++k) {
        const float tk = (float)k + 0.5f;
        const float v  = __powf(tk, am1) * __expf(-tk * invth);
        w[k] = v; wsum += v;
    }
    const float wn = 0.5f / wsum;  // fold nmul-mean 0.5 into weights
#pragma unroll
    for (int k = 0; k < CH; ++k) w[k] *= wn;

    // ---- state, routing ring, staging registers ----
    float SP = 1e-3f, MW = 1e-3f, SM = 1e-3f, SUZ = 1e-3f, SLZ = 1e-3f;
    float facc[CH];
#pragma unroll
    for (int k = 0; k < CH; ++k) facc[k] = 0.f;
    float oflow[CH];

    float4 xR[6];  // x chunk: 15 rows x 96 floats = 360 float4 (i=5: lanes<40)
    float4 dR[8];  // dy chunk: 15 rows x 128 floats = 480 float4 (i=7: lanes<32)

    auto loadR = [&](int c) {
        const int cc = c < NCHUNK ? c : NCHUNK - 1;
        const int tb = cc * CH;
#pragma unroll
        for (int i = 0; i < 6; ++i) {
            int idx = i * 64 + lane;
            idx = idx < 360 ? idx : 359;
            const int row = idx / 24;
            const int col = idx - row * 24;
            int t = tb + row; t = t < TS ? t : TS - 1;
            xR[i] = *(const float4*)(x_phy + (size_t)t * (NG * 3) + g0r * 3 + col * 4);
        }
#pragma unroll
        for (int i = 0; i < 8; ++i) {
            int idx = i * 64 + lane;
            idx = idx < 480 ? idx : 479;
            const int row = idx >> 5;
            const int col = idx & 31;
            int t = tb + row; t = t < TS ? t : TS - 1;
            dR[i] = *(const float4*)(params_dy + (size_t)t * (NG * 4) + g0r * 4 + col * 4);
        }
    };

    auto writeB = [&](int b) {
        float* xd = xb[b];
#pragma unroll
        for (int i = 0; i < 6; ++i) {
            const int idx = i * 64 + lane;
            if (idx < 360) *(float4*)(xd + idx * 4) = xR[i];
        }
#pragma unroll
        for (int i = 0; i < 8; ++i) {
            const int idx = i * 64 + lane;  // == row*32+col: plane slot directly
            if (idx < 480) {
                db[b][0][idx] = dR[i].x;
                db[b][1][idx] = dR[i].y;
                db[b][2][idx] = dR[i].z;
                db[b][3][idx] = dR[i].w;
            }
        }
    };

    auto compute = [&](int c) {
        const float* xd = xb[c & 1];
        const float* d0 = db[c & 1][m];      // beta plane for this m
        const float* d2 = db[c & 1][2 + m];  // betaet plane for this m
#pragma unroll
        for (int j = 0; j < CH; ++j) {
            const float Pt   = xd[(j * 32 + cl) * 3 + 0];
            const float Tt   = xd[(j * 32 + cl) * 3 + 1];
            const float PETt = xd[(j * 32 + cl) * 3 + 2];
            const float beta   = d0[j * 32 + cl] * 5.f  + 1.f;
            const float betaet = d2[j * 32 + cl] * 4.7f + 0.3f;

            // snow bucket
            const float rain = (Tt >= TTp) ? Pt : 0.f;
            const float snow = Pt - rain;
            SP += snow;
            const float melt = fminf(fmaxf(CFMAX * (Tt - TTp), 0.f), SP);
            MW += melt; SP -= melt;
            const float refr = fminf(fmaxf(CFRC * (TTp - Tt), 0.f), MW);
            SP += refr; MW -= refr;
            const float tosoil = fmaxf(MW - CWH * SP, 0.f);
            MW -= tosoil;

            // soil bucket
            const float sw   = fminf(__powf(SM * invFC, beta), 1.f);
            const float rts  = rain + tosoil;
            const float rech = rts * sw;
            SM += rts - rech;
            const float exc = fmaxf(SM - FC, 0.f);
            SM -= exc;
            const float ef = __powf(fminf(SM * invLPFC, 1.f), betaet);
            const float ET = fminf(SM, PETt * ef);
            SM = fmaxf(SM - ET, 1e-5f);
            const float cap = fminf(SLZ, Cc * SLZ * (1.f - fminf(SM * invFC, 1.f)));
            SM  = fmaxf(SM + cap, 1e-5f);
            SLZ = fmaxf(SLZ - cap, 1e-5f);

            // groundwater buckets
            SUZ += rech + exc;
            const float perc = fminf(SUZ, PERCp);
            SUZ -= perc;
            const float Q0 = K0 * fmaxf(SUZ - UZL, 0.f);
            SUZ -= Q0;
            const float Q1 = K1 * SUZ;
            SUZ -= Q1;
            SLZ += perc;
            const float gw = fminf(SLZ, gwcap);
            SLZ -= gw;
            const float Q2 = K2 * SLZ;
            SLZ -= Q2;
            const float Qt = Q0 + Q1 + Q2;

            // nmul mean (0.5 folded into w) + fused causal UH ring
            const float Qc = Qt + __shfl_xor(Qt, 32);
#pragma unroll
            for (int k = 0; k < CH; ++k)
                facc[(j + k) % CH] = fmaf(w[k], Qc, facc[(j + k) % CH]);
            oflow[j]  = facc[j];   // flow[t] complete; buffered, stored at chunk end
            facc[j]   = 0.f;       // recycle slot for t+15 (pure reg, no VMEM hazard)
        }
    };

    // prologue: chunk0 -> LDS buf0; chunk1 in flight in registers
    loadR(0);
    writeB(0);
    loadR(1);

    for (int c = 0; c < NCHUNK; ++c) {
        writeB((c + 1) & 1);   // R (chunk c+1) -> LDS; its loads are a full chunk old
        loadR(c + 2);          // prefetch chunk c+2; stays in flight through compute
        compute(c);            // LDS + reg only: no vmcnt waits inside

        if (g < NG && lane < 32) {
            const int tb = c * CH;
#pragma unroll
            for (int j = 0; j < CH; ++j) {
                const int t = tb + j;
                if (t < TS) out[(size_t)t * NG + g] = oflow[j];
            }
        }
    }
}

extern "C" void kernel_launch(void* const* d_in, const int* in_sizes, int n_in,
                              void* d_out, int out_size, void* d_ws, size_t ws_size,
                              hipStream_t stream) {
    const float* x_phy = (const float*)d_in[0];
    const float* ac    = (const float*)d_in[1];
    // d_in[2] = elev_all: unused by the reference forward
    const float* pdy   = (const float*)d_in[3];
    const float* pst   = (const float*)d_in[4];
    float* out = (float*)d_out;

    const int grid = (NG + 31) / 32;  // 313 single-wave blocks -> every CU busy
    hbv_fused<<<grid, 64, 0, stream>>>(x_phy, ac, pdy, pst, out);
}

// Round 4
// 378.910 us; speedup vs baseline: 2.3558x; 2.3031x over previous
//
#include <hip/hip_runtime.h>

// HBV 2.0 fused scan + gamma-UH routing, MI355X (gfx950). Round 4.
// R1/R2 post-mortem: identical ~740us despite removing all inner-loop VMEM ->
// bottleneck is instruction count. VALUBusy 22% at ~1.2 waves/CU means ~85%
// per-SIMD issue -> ~900 VALU inst/step vs ~95 expected. Culprit: __powf on
// HIP lowers to __ocml_pow_f32 (full special-case pow, ~400 inst), 2x/step.
// R3 hit a glibc math.h macro clash with __exp2f/__log2f; R4 uses the raw
// AMDGCN builtins (v_log_f32 / v_exp_f32) which bypass libm and OCML.

#define TS 730
#define NG 10000
#define CH 15
#define NCHUNK 49  // 49*15 = 735 >= 730; tail loads clamped, stores masked

// x^b for x>0 via native v_log_f32 + v_exp_f32 (2 transcendental inst)
__device__ __forceinline__ float powpos(float x, float b) {
    return __builtin_amdgcn_exp2f(b * __builtin_amdgcn_logf(x));
}

__global__ __launch_bounds__(64, 1) void hbv_fused(
    const float* __restrict__ x_phy,
    const float* __restrict__ ac_all,
    const float* __restrict__ params_dy,
    const float* __restrict__ params_stat,
    float* __restrict__ out)
{
    // LDS double buffers. xb: [j][cell][3] (stride-3 reads: conflict-free).
    // db: 4 planes [beta_m0, beta_m1, betaet_m0, betaet_m1] x [j][cell]
    // (stride-1 reads; 2-way alias across wave halves is free).
    __shared__ float xb[2][CH * 32 * 3];
    __shared__ float db[2][4][CH * 32];

    const int lane = threadIdx.x & 63;
    const int m    = lane >> 5;            // nmul component
    const int cell = lane & 31;
    const int g0   = blockIdx.x * 32;
    const int g    = g0 + cell;
    const int gl   = g < NG ? g : NG - 1;
    // last block: shift the 32-cell load window left so staging never reads OOB
    const int g0r  = (g0 <= NG - 32) ? g0 : NG - 32;
    const int co   = cell + (g0 - g0r);
    const int cl   = co < 31 ? co : 31;    // LDS cell slot for this thread

    // ---- static params: params_stat[g, i*2 + m]; routing at 28,29 ----
    const float* ps = params_stat + (size_t)gl * 30;
    const float FC    = ps[0  + m] * 950.f   + 50.f;
    const float K0    = ps[2  + m] * 0.85f   + 0.05f;
    const float K1    = ps[4  + m] * 0.49f   + 0.01f;
    const float K2    = ps[6  + m] * 0.199f  + 0.001f;
    const float LP    = ps[8  + m] * 0.8f    + 0.2f;
    const float PERCp = ps[10 + m] * 10.f;
    const float UZL   = ps[12 + m] * 100.f;
    const float TTp   = ps[14 + m] * 5.f     - 2.5f;
    const float CFMAX = ps[16 + m] * 9.5f    + 0.5f;
    const float CFR   = ps[18 + m] * 0.1f;
    const float CWH   = ps[20 + m] * 0.2f;
    const float Cc    = ps[22 + m];
    const float RT    = ps[24 + m] * 20.f;
    const float ACp   = ps[26 + m] * 2500.f;
    const float ra    = ps[28] * 2.9f;
    const float rb    = ps[29] * 6.5f;

    const float Acv     = ac_all[gl];
    const float invFC   = 1.f / FC;
    const float invLPFC = 1.f / (LP * FC);
    const float CFRC    = CFR * CFMAX;
    const float gwcap   = RT * fminf(fmaxf(1.f - Acv / (ACp + 1e-5f), 0.f), 1.f);

    // ---- UH weights (normalization cancels gammaln/theta^-a prefactor) ----
    // w_k ∝ t^(a-1) * exp(-t/theta) = exp2((a-1)*log2(t) - (t/theta)*log2(e))
    const float a     = fmaxf(ra, 0.f) + 0.1f;
    const float th    = fmaxf(rb, 0.f) + 0.5f;
    const float am1   = a - 1.f;
    const float nl2e  = 1.44269504f / th;
    float w[CH];
    float wsum = 0.f;
#pragma unroll
    for (int k = 0; k < CH; ++k) {
        const float tk = (float)k + 0.5f;
        const float v  = __builtin_amdgcn_exp2f(am1 * __builtin_amdgcn_logf(tk) - tk * nl2e);
        w[k] = v; wsum += v;
    }
    const float wn = 0.5f / wsum;  // fold nmul-mean 0.5 into weights
#pragma unroll
    for (int k = 0; k < CH; ++k) w[k] *= wn;

    // ---- state, routing ring, staging registers ----
    float SP = 1e-3f, MW = 1e-3f, SM = 1e-3f, SUZ = 1e-3f, SLZ = 1e-3f;
    float facc[CH];
#pragma unroll
    for (int k = 0; k < CH; ++k) facc[k] = 0.f;
    float oflow[CH];

    float4 xR[6];  // x chunk: 15 rows x 96 floats = 360 float4
    float4 dR[8];  // dy chunk: 15 rows x 128 floats = 480 float4

    auto loadR = [&](int c) {
        const int cc = c < NCHUNK ? c : NCHUNK - 1;
        const int tb = cc * CH;
#pragma unroll
        for (int i = 0; i < 6; ++i) {
            int idx = i * 64 + lane;
            idx = idx < 360 ? idx : 359;
            const int row = idx / 24;
            const int col = idx - row * 24;
            int t = tb + row; t = t < TS ? t : TS - 1;
            xR[i] = *(const float4*)(x_phy + (size_t)t * (NG * 3) + g0r * 3 + col * 4);
        }
#pragma unroll
        for (int i = 0; i < 8; ++i) {
            int idx = i * 64 + lane;
            idx = idx < 480 ? idx : 479;
            const int row = idx >> 5;
            const int col = idx & 31;
            int t = tb + row; t = t < TS ? t : TS - 1;
            dR[i] = *(const float4*)(params_dy + (size_t)t * (NG * 4) + g0r * 4 + col * 4);
        }
    };

    auto writeB = [&](int b) {
        float* xd = xb[b];
#pragma unroll
        for (int i = 0; i < 6; ++i) {
            const int idx = i * 64 + lane;
            if (idx < 360) *(float4*)(xd + idx * 4) = xR[i];
        }
#pragma unroll
        for (int i = 0; i < 8; ++i) {
            const int idx = i * 64 + lane;  // == row*32+col: plane slot directly
            if (idx < 480) {
                db[b][0][idx] = dR[i].x;
                db[b][1][idx] = dR[i].y;
                db[b][2][idx] = dR[i].z;
                db[b][3][idx] = dR[i].w;
            }
        }
    };

    auto compute = [&](int c) {
        const float* xd = xb[c & 1];
        const float* d0 = db[c & 1][m];      // beta plane for this m
        const float* d2 = db[c & 1][2 + m];  // betaet plane for this m
#pragma unroll
        for (int j = 0; j < CH; ++j) {
            const float Pt   = xd[(j * 32 + cl) * 3 + 0];
            const float Tt   = xd[(j * 32 + cl) * 3 + 1];
            const float PETt = xd[(j * 32 + cl) * 3 + 2];
            const float beta   = d0[j * 32 + cl] * 5.f  + 1.f;
            const float betaet = d2[j * 32 + cl] * 4.7f + 0.3f;

            // snow bucket
            const float rain = (Tt >= TTp) ? Pt : 0.f;
            const float snow = Pt - rain;
            SP += snow;
            const float melt = fminf(fmaxf(CFMAX * (Tt - TTp), 0.f), SP);
            MW += melt; SP -= melt;
            const float refr = fminf(fmaxf(CFRC * (TTp - Tt), 0.f), MW);
            SP += refr; MW -= refr;
            const float tosoil = fmaxf(MW - CWH * SP, 0.f);
            MW -= tosoil;

            // soil bucket (SM*invFC >= 1e-8 > 0: native log safe)
            const float sw   = fminf(powpos(SM * invFC, beta), 1.f);
            const float rts  = rain + tosoil;
            const float rech = rts * sw;
            SM += rts - rech;
            const float exc = fmaxf(SM - FC, 0.f);
            SM -= exc;
            const float ef = powpos(fminf(SM * invLPFC, 1.f), betaet);
            const float ET = fminf(SM, PETt * ef);
            SM = fmaxf(SM - ET, 1e-5f);
            const float cap = fminf(SLZ, Cc * SLZ * (1.f - fminf(SM * invFC, 1.f)));
            SM  = fmaxf(SM + cap, 1e-5f);
            SLZ = fmaxf(SLZ - cap, 1e-5f);

            // groundwater buckets
            SUZ += rech + exc;
            const float perc = fminf(SUZ, PERCp);
            SUZ -= perc;
            const float Q0 = K0 * fmaxf(SUZ - UZL, 0.f);
            SUZ -= Q0;
            const float Q1 = K1 * SUZ;
            SUZ -= Q1;
            SLZ += perc;
            const float gw = fminf(SLZ, gwcap);
            SLZ -= gw;
            const float Q2 = K2 * SLZ;
            SLZ -= Q2;
            const float Qt = Q0 + Q1 + Q2;

            // nmul mean (0.5 folded into w) + fused causal UH ring
            const float Qc = Qt + __shfl_xor(Qt, 32);
#pragma unroll
            for (int k = 0; k < CH; ++k)
                facc[(j + k) % CH] = fmaf(w[k], Qc, facc[(j + k) % CH]);
            oflow[j]  = facc[j];   // flow[t] complete; stored at chunk end
            facc[j]   = 0.f;       // recycle slot for t+15
        }
    };

    // prologue: chunk0 -> LDS buf0; chunk1 in flight in registers
    loadR(0);
    writeB(0);
    loadR(1);

    for (int c = 0; c < NCHUNK; ++c) {
        writeB((c + 1) & 1);   // chunk c+1 regs -> LDS (loads issued a chunk ago)
        loadR(c + 2);          // prefetch chunk c+2; in flight through compute
        compute(c);            // LDS + reg only inside

        if (g < NG && lane < 32) {
            const int tb = c * CH;
#pragma unroll
            for (int j = 0; j < CH; ++j) {
                const int t = tb + j;
                if (t < TS) out[(size_t)t * NG + g] = oflow[j];
            }
        }
    }
}

extern "C" void kernel_launch(void* const* d_in, const int* in_sizes, int n_in,
                              void* d_out, int out_size, void* d_ws, size_t ws_size,
                              hipStream_t stream) {
    const float* x_phy = (const float*)d_in[0];
    const float* ac    = (const float*)d_in[1];
    // d_in[2] = elev_all: unused by the reference forward
    const float* pdy   = (const float*)d_in[3];
    const float* pst   = (const float*)d_in[4];
    float* out = (float*)d_out;

    const int grid = (NG + 31) / 32;  // 313 single-wave blocks
    hbv_fused<<<grid, 64, 0, stream>>>(x_phy, ac, pdy, pst, out);
}

// Round 6
// 335.996 us; speedup vs baseline: 2.6567x; 1.1277x over previous
//
#include <hip/hip_runtime.h>

// HBV 2.0 fused scan + gamma-UH routing, MI355X (gfx950). Round 6.
// R4: VGPR=88 < ~130 live -> allocator spilled staging regs (WRITE_SIZE
// +2.3MB scratch leak). R5 replaced staging with global_load_lds DMA but
// crashed: precomputed chunk-relative DMA rows 0..14 read t=730..734 on the
// last chunk -> 575KB/640KB OOB -> page fault. R6 = R5 with the last-chunk
// issue clamping absolute t to TS-1 per lane (exactly in-bounds; verified
// max element = TS*NG*3-1 / TS*NG*4-1). Both issue paths emit exactly 14
// DMAs so the vmcnt(14) double-buffer choreography is unchanged.

#define TS 730
#define NG 10000
#define CH 15
#define NCHUNK 49            // 49*15 = 735 >= 730
#define XSTRIDE (NG * 3)
#define DSTRIDE (NG * 4)

#define AS1 __attribute__((address_space(1)))
#define AS3 __attribute__((address_space(3)))
// gfx9/CDNA s_waitcnt simm16: vmcnt[3:0]=simm[3:0], vmcnt[5:4]=simm[15:14],
// expcnt=simm[6:4], lgkmcnt=simm[11:8]
#define WAIT_VMCNT(n) __builtin_amdgcn_s_waitcnt(((n) & 15) | 0x70 | 0xF00 | (((n) >> 4) << 14))
#define WAIT_LGKM0    __builtin_amdgcn_s_waitcnt(0xC07F)

__device__ __forceinline__ void gload16(const float* g, float* l) {
    __builtin_amdgcn_global_load_lds((const AS1 void*)g, (AS3 void*)l, 16, 0, 0);
}
// x^b for x>0 via native v_log_f32 + v_exp_f32
__device__ __forceinline__ float powpos(float x, float b) {
    return __builtin_amdgcn_exp2f(b * __builtin_amdgcn_logf(x));
}

__global__ __launch_bounds__(64, 1) void hbv_fused(
    const float* __restrict__ x_phy,
    const float* __restrict__ ac_all,
    const float* __restrict__ params_dy,
    const float* __restrict__ params_stat,
    float* __restrict__ out)
{
    // LDS double buffers in exact DMA lane order (lane i -> base + i*16B).
    // x chunk: 15 rows x 96 floats = 1440, padded to 6 inst x 256 = 1536.
    // d chunk: 15 rows x 128 floats = 1920, padded to 8 inst x 256 = 2048.
    __shared__ float xls0[1536], xls1[1536];
    __shared__ float dls0[2048], dls1[2048];

    const int lane = threadIdx.x & 63;
    const int m    = lane >> 5;            // nmul component
    const int cell = lane & 31;
    const int g0   = blockIdx.x * 32;
    const int g    = g0 + cell;
    const int gl   = g < NG ? g : NG - 1;
    // last block: shift 32-cell window left so staging never reads OOB
    const int g0r  = (g0 <= NG - 32) ? g0 : NG - 32;
    const int co   = cell + (g0 - g0r);
    const int cl   = co < 31 ? co : 31;    // LDS cell slot (stores masked for dups)

    // ---- static params: params_stat[g, i*2 + m]; routing at 28,29 ----
    const float* ps = params_stat + (size_t)gl * 30;
    const float FC    = ps[0  + m] * 950.f   + 50.f;
    const float K0    = ps[2  + m] * 0.85f   + 0.05f;
    const float K1    = ps[4  + m] * 0.49f   + 0.01f;
    const float K2    = ps[6  + m] * 0.199f  + 0.001f;
    const float LP    = ps[8  + m] * 0.8f    + 0.2f;
    const float PERCp = ps[10 + m] * 10.f;
    const float UZL   = ps[12 + m] * 100.f;
    const float TTp   = ps[14 + m] * 5.f     - 2.5f;
    const float CFMAX = ps[16 + m] * 9.5f    + 0.5f;
    const float CFR   = ps[18 + m] * 0.1f;
    const float CWH   = ps[20 + m] * 0.2f;
    const float Cc    = ps[22 + m];
    const float RT    = ps[24 + m] * 20.f;
    const float ACp   = ps[26 + m] * 2500.f;
    const float ra    = ps[28] * 2.9f;
    const float rb    = ps[29] * 6.5f;

    const float Acv     = ac_all[gl];
    const float invFC   = 1.f / FC;
    const float invLPFC = 1.f / (LP * FC);
    const float CFRC    = CFR * CFMAX;
    const float gwcap   = RT * fminf(fmaxf(1.f - Acv / (ACp + 1e-5f), 0.f), 1.f);

    // ---- UH weights (normalization cancels gammaln/theta^-a prefactor) ----
    const float a     = fmaxf(ra, 0.f) + 0.1f;
    const float th    = fmaxf(rb, 0.f) + 0.5f;
    const float am1   = a - 1.f;
    const float nl2e  = 1.44269504f / th;
    float w[CH];
    float wsum = 0.f;
#pragma unroll
    for (int k = 0; k < CH; ++k) {
        const float tk = (float)k + 0.5f;
        const float v  = __builtin_amdgcn_exp2f(am1 * __builtin_amdgcn_logf(tk) - tk * nl2e);
        w[k] = v; wsum += v;
    }
    const float wn = 0.5f / wsum;  // fold nmul-mean 0.5 into weights
#pragma unroll
    for (int k = 0; k < CH; ++k) w[k] *= wn;

    // ---- per-lane DMA source offsets (float units), chunk-relative ----
    int offx[6], offd[8];
#pragma unroll
    for (int i = 0; i < 6; ++i) {
        int idx = i * 64 + lane;
        idx = idx < 360 ? idx : 359;       // clamped lanes dup last element
        const int row = idx / 24;
        const int col = idx - row * 24;
        offx[i] = row * XSTRIDE + col * 4;
    }
#pragma unroll
    for (int i = 0; i < 8; ++i) {
        int idx = i * 64 + lane;
        idx = idx < 480 ? idx : 479;
        const int row = idx >> 5;
        const int col = idx & 31;
        offd[i] = row * DSTRIDE + col * 4;
    }
    const float* xbase = x_phy     + (size_t)g0r * 3;
    const float* dbase = params_dy + (size_t)g0r * 4;

    auto issue = [&](int cc, float* xl, float* dl) {  // exactly 14 DMA ops
        if (cc == NCHUNK - 1) {
            // last chunk: rows 10..14 would hit t=730..734 -> clamp abs t.
            // Uniform branch, executed once; recompute per-lane addresses.
#pragma unroll
            for (int i = 0; i < 6; ++i) {
                int idx = i * 64 + lane; idx = idx < 360 ? idx : 359;
                const int row = idx / 24, col = idx - row * 24;
                int t = cc * CH + row; t = t < TS ? t : TS - 1;
                gload16(xbase + (size_t)t * XSTRIDE + col * 4, xl + i * 256);
            }
#pragma unroll
            for (int i = 0; i < 8; ++i) {
                int idx = i * 64 + lane; idx = idx < 480 ? idx : 479;
                const int row = idx >> 5, col = idx & 31;
                int t = cc * CH + row; t = t < TS ? t : TS - 1;
                gload16(dbase + (size_t)t * DSTRIDE + col * 4, dl + i * 256);
            }
        } else {
            const float* xp = xbase + (size_t)cc * CH * XSTRIDE;
            const float* dp = dbase + (size_t)cc * CH * DSTRIDE;
#pragma unroll
            for (int i = 0; i < 6; ++i) gload16(xp + offx[i], xl + i * 256);
#pragma unroll
            for (int i = 0; i < 8; ++i) gload16(dp + offd[i], dl + i * 256);
        }
    };

    // ---- state + routing ring ----
    float SP = 1e-3f, MW = 1e-3f, SM = 1e-3f, SUZ = 1e-3f, SLZ = 1e-3f;
    float facc[CH];
#pragma unroll
    for (int k = 0; k < CH; ++k) facc[k] = 0.f;

    const bool doStore = (g < NG) && (lane < 32);

    auto chunk = [&](int c, const float* xl, const float* dl) {
        float ofl[CH];
#pragma unroll
        for (int j = 0; j < CH; ++j) {
            const float Pt   = xl[j * 96 + cl * 3 + 0];
            const float Tt   = xl[j * 96 + cl * 3 + 1];
            const float PETt = xl[j * 96 + cl * 3 + 2];
            const float4 dv  = *(const float4*)&dl[j * 128 + cl * 4];  // b128 bcast
            const float beta   = (m ? dv.y : dv.x) * 5.f  + 1.f;
            const float betaet = (m ? dv.w : dv.z) * 4.7f + 0.3f;

            // snow bucket
            const float rain = (Tt >= TTp) ? Pt : 0.f;
            SP += Pt - rain;
            const float melt = fminf(fmaxf(CFMAX * (Tt - TTp), 0.f), SP);
            MW += melt; SP -= melt;
            const float refr = fminf(fmaxf(CFRC * (TTp - Tt), 0.f), MW);
            SP += refr; MW -= refr;
            const float tosoil = fmaxf(MW - CWH * SP, 0.f);
            MW -= tosoil;

            // soil bucket (SM > 0 strictly: native log safe)
            const float sw   = fminf(powpos(SM * invFC, beta), 1.f);
            const float rts  = rain + tosoil;
            SM = fmaf(rts, 1.f - sw, SM);
            const float exc = fmaxf(SM - FC, 0.f);
            SM = fminf(SM, FC);
            const float ef = powpos(fminf(SM * invLPFC, 1.f), betaet);
            const float ET = fminf(SM, PETt * ef);
            SM = fmaxf(SM - ET, 1e-5f);
            // Cc<=1, factor<=1 -> product <= SLZ; reference min is redundant
            const float cap = Cc * SLZ * (1.f - fminf(SM * invFC, 1.f));
            SM  = fmaxf(SM + cap, 1e-5f);
            SLZ = fmaxf(SLZ - cap, 1e-5f);

            // groundwater buckets
            SUZ += rts * sw + exc;
            const float perc = fminf(SUZ, PERCp);
            SUZ -= perc;
            const float Q0 = K0 * fmaxf(SUZ - UZL, 0.f);
            SUZ -= Q0;
            const float Q1 = K1 * SUZ;
            SUZ -= Q1;
            SLZ += perc;
            const float gw = fminf(SLZ, gwcap);
            SLZ -= gw;
            const float Q2 = K2 * SLZ;
            SLZ -= Q2;
            const float Qt = Q0 + Q1 + Q2;

            // nmul mean (0.5 folded into w) + fused causal UH ring
            const float Qc = Qt + __shfl_xor(Qt, 32);
#pragma unroll
            for (int k = 0; k < CH; ++k)
                facc[(j + k) % CH] = fmaf(w[k], Qc, facc[(j + k) % CH]);
            ofl[j]  = facc[j];   // flow[t] complete
            facc[j] = 0.f;       // recycle slot for t+15
        }
        // stores BEFORE next issue() so the next chunk's 14 DMAs stay the
        // newest vmcnt entries (WAIT_VMCNT(14) then allows exactly them)
        if (doStore) {
            float* op = out + (size_t)c * CH * NG + g;
            const int tb = c * CH;
#pragma unroll
            for (int j = 0; j < CH; ++j)
                if (tb + j < TS) op[(size_t)j * NG] = ofl[j];
        }
    };

    // prolog: both buffers' DMAs in flight
    issue(0, xls0, dls0);
    issue(1, xls1, dls1);

    for (int cp = 0; cp < 24; ++cp) {
        const int c0 = 2 * cp;
        WAIT_VMCNT(14);                    // chunk c0 DMAs (+older stores) drained
        chunk(c0, xls0, dls0);
        WAIT_LGKM0;                        // ds_reads of xls0/dls0 retired (WAR)
        issue(c0 + 2, xls0, dls0);
        WAIT_VMCNT(14);
        chunk(c0 + 1, xls1, dls1);
        WAIT_LGKM0;
        if (cp < 23) issue(c0 + 3, xls1, dls1);
    }
    WAIT_VMCNT(14);                        // chunk-48 DMAs drained (14 newest
                                           // entries are 14 of the 15 stores)
    chunk(48, xls0, dls0);
}

extern "C" void kernel_launch(void* const* d_in, const int* in_sizes, int n_in,
                              void* d_out, int out_size, void* d_ws, size_t ws_size,
                              hipStream_t stream) {
    const float* x_phy = (const float*)d_in[0];
    const float* ac    = (const float*)d_in[1];
    // d_in[2] = elev_all: unused by the reference forward
    const float* pdy   = (const float*)d_in[3];
    const float* pst   = (const float*)d_in[4];
    float* out = (float*)d_out;

    const int grid = (NG + 31) / 32;  // 313 single-wave blocks
    hbv_fused<<<grid, 64, 0, stream>>>(x_phy, ac, pdy, pst, out);
}

// Round 7
// 322.977 us; speedup vs baseline: 2.7638x; 1.0403x over previous
//
#include <hip/hip_runtime.h>

// HBV 2.0 fused scan + gamma-UH routing, MI355X (gfx950). Round 7.
// R6 = 181us (~595 cyc/step) vs ~220 issue floor: ~380 cyc/step stall.
// Diagnosis: per-step __shfl_xor (ds_permute) shares the lgkmcnt FIFO with
// the ds_reads; waiting for the shuffle each step also drains all prefetched
// reads -> exposed DS latency every step. R7: both nmul halves run the full
// 15-tap ring on their OWN Qm (flow = sum_w Qm0 + sum_w Qm1 by linearity);
// the cross-half combine is a per-chunk batched epilogue (15 ds_permute +
// add + store). Inner loop now has only 4 prefetchable ds_reads and no other
// DS ops; inputs are software-pipelined one step ahead.

#define TS 730
#define NG 10000
#define CH 15
#define NCHUNK 49            // 49*15 = 735 >= 730
#define XSTRIDE (NG * 3)
#define DSTRIDE (NG * 4)

#define AS1 __attribute__((address_space(1)))
#define AS3 __attribute__((address_space(3)))
// gfx9/CDNA s_waitcnt simm16: vmcnt[3:0]=simm[3:0], vmcnt[5:4]=simm[15:14],
// expcnt=simm[6:4], lgkmcnt=simm[11:8]
#define WAIT_VMCNT(n) __builtin_amdgcn_s_waitcnt(((n) & 15) | 0x70 | 0xF00 | (((n) >> 4) << 14))
#define WAIT_LGKM0    __builtin_amdgcn_s_waitcnt(0xC07F)

__device__ __forceinline__ void gload16(const float* g, float* l) {
    __builtin_amdgcn_global_load_lds((const AS1 void*)g, (AS3 void*)l, 16, 0, 0);
}
// x^b for x>0 via native v_log_f32 + v_exp_f32
__device__ __forceinline__ float powpos(float x, float b) {
    return __builtin_amdgcn_exp2f(b * __builtin_amdgcn_logf(x));
}

__global__ __launch_bounds__(64, 1) void hbv_fused(
    const float* __restrict__ x_phy,
    const float* __restrict__ ac_all,
    const float* __restrict__ params_dy,
    const float* __restrict__ params_stat,
    float* __restrict__ out)
{
    // LDS double buffers in exact DMA lane order (lane i -> base + i*16B).
    __shared__ float xls0[1536], xls1[1536];
    __shared__ float dls0[2048], dls1[2048];

    const int lane = threadIdx.x & 63;
    const int m    = lane >> 5;            // nmul component
    const int cell = lane & 31;
    const int g0   = blockIdx.x * 32;
    const int g    = g0 + cell;
    const int gl   = g < NG ? g : NG - 1;
    // last block: shift 32-cell window left so staging never reads OOB
    const int g0r  = (g0 <= NG - 32) ? g0 : NG - 32;
    const int co   = cell + (g0 - g0r);
    const int cl   = co < 31 ? co : 31;    // LDS cell slot (stores masked for dups)

    // ---- static params: params_stat[g, i*2 + m]; routing at 28,29 ----
    const float* ps = params_stat + (size_t)gl * 30;
    const float FC    = ps[0  + m] * 950.f   + 50.f;
    const float K0    = ps[2  + m] * 0.85f   + 0.05f;
    const float K1    = ps[4  + m] * 0.49f   + 0.01f;
    const float K2    = ps[6  + m] * 0.199f  + 0.001f;
    const float LP    = ps[8  + m] * 0.8f    + 0.2f;
    const float PERCp = ps[10 + m] * 10.f;
    const float UZL   = ps[12 + m] * 100.f;
    const float TTp   = ps[14 + m] * 5.f     - 2.5f;
    const float CFMAX = ps[16 + m] * 9.5f    + 0.5f;
    const float CFR   = ps[18 + m] * 0.1f;
    const float CWH   = ps[20 + m] * 0.2f;
    const float Cc    = ps[22 + m];
    const float RT    = ps[24 + m] * 20.f;
    const float ACp   = ps[26 + m] * 2500.f;
    const float ra    = ps[28] * 2.9f;
    const float rb    = ps[29] * 6.5f;

    const float Acv     = ac_all[gl];
    const float invFC   = 1.f / FC;
    const float invLPFC = 1.f / (LP * FC);
    const float CFRC    = CFR * CFMAX;
    const float gwcap   = RT * fminf(fmaxf(1.f - Acv / (ACp + 1e-5f), 0.f), 1.f);

    // ---- UH weights (normalization cancels gammaln/theta^-a prefactor) ----
    const float a     = fmaxf(ra, 0.f) + 0.1f;
    const float th    = fmaxf(rb, 0.f) + 0.5f;
    const float am1   = a - 1.f;
    const float nl2e  = 1.44269504f / th;
    float w[CH];
    float wsum = 0.f;
#pragma unroll
    for (int k = 0; k < CH; ++k) {
        const float tk = (float)k + 0.5f;
        const float v  = __builtin_amdgcn_exp2f(am1 * __builtin_amdgcn_logf(tk) - tk * nl2e);
        w[k] = v; wsum += v;
    }
    const float wn = 0.5f / wsum;  // fold nmul-mean 0.5 into weights
#pragma unroll
    for (int k = 0; k < CH; ++k) w[k] *= wn;

    // ---- per-lane DMA source offsets (float units), chunk-relative ----
    int offx[6], offd[8];
#pragma unroll
    for (int i = 0; i < 6; ++i) {
        int idx = i * 64 + lane;
        idx = idx < 360 ? idx : 359;
        const int row = idx / 24;
        const int col = idx - row * 24;
        offx[i] = row * XSTRIDE + col * 4;
    }
#pragma unroll
    for (int i = 0; i < 8; ++i) {
        int idx = i * 64 + lane;
        idx = idx < 480 ? idx : 479;
        const int row = idx >> 5;
        const int col = idx & 31;
        offd[i] = row * DSTRIDE + col * 4;
    }
    const float* xbase = x_phy     + (size_t)g0r * 3;
    const float* dbase = params_dy + (size_t)g0r * 4;

    auto issue = [&](int cc, float* xl, float* dl) {  // exactly 14 DMA ops
        if (cc == NCHUNK - 1) {
            // last chunk: rows 10..14 would hit t=730..734 -> clamp abs t
#pragma unroll
            for (int i = 0; i < 6; ++i) {
                int idx = i * 64 + lane; idx = idx < 360 ? idx : 359;
                const int row = idx / 24, col = idx - row * 24;
                int t = cc * CH + row; t = t < TS ? t : TS - 1;
                gload16(xbase + (size_t)t * XSTRIDE + col * 4, xl + i * 256);
            }
#pragma unroll
            for (int i = 0; i < 8; ++i) {
                int idx = i * 64 + lane; idx = idx < 480 ? idx : 479;
                const int row = idx >> 5, col = idx & 31;
                int t = cc * CH + row; t = t < TS ? t : TS - 1;
                gload16(dbase + (size_t)t * DSTRIDE + col * 4, dl + i * 256);
            }
        } else {
            const float* xp = xbase + (size_t)cc * CH * XSTRIDE;
            const float* dp = dbase + (size_t)cc * CH * DSTRIDE;
#pragma unroll
            for (int i = 0; i < 6; ++i) gload16(xp + offx[i], xl + i * 256);
#pragma unroll
            for (int i = 0; i < 8; ++i) gload16(dp + offd[i], dl + i * 256);
        }
    };

    // ---- state + per-half routing ring ----
    float SP = 1e-3f, MW = 1e-3f, SM = 1e-3f, SUZ = 1e-3f, SLZ = 1e-3f;
    float facc[CH];
#pragma unroll
    for (int k = 0; k < CH; ++k) facc[k] = 0.f;

    const bool doStore = (g < NG) && (lane < 32);

    auto chunk = [&](int c, const float* xl, const float* dl) {
        float ofl[CH];
        // software pipeline: inputs for step j+1 loaded during step j
        float Pc = xl[cl * 3 + 0], Tc = xl[cl * 3 + 1], Ec = xl[cl * 3 + 2];
        float4 dvc = *(const float4*)&dl[cl * 4];
#pragma unroll
        for (int j = 0; j < CH; ++j) {
            float Pn, Tn, En; float4 dvn;
            if (j < CH - 1) {
                Pn  = xl[(j + 1) * 96 + cl * 3 + 0];
                Tn  = xl[(j + 1) * 96 + cl * 3 + 1];
                En  = xl[(j + 1) * 96 + cl * 3 + 2];
                dvn = *(const float4*)&dl[(j + 1) * 128 + cl * 4];
            }
            const float Pt = Pc, Tt = Tc, PETt = Ec;
            const float beta   = (m ? dvc.y : dvc.x) * 5.f  + 1.f;
            const float betaet = (m ? dvc.w : dvc.z) * 4.7f + 0.3f;

            // snow bucket
            const float rain = (Tt >= TTp) ? Pt : 0.f;
            SP += Pt - rain;
            const float melt = fminf(fmaxf(CFMAX * (Tt - TTp), 0.f), SP);
            MW += melt; SP -= melt;
            const float refr = fminf(fmaxf(CFRC * (TTp - Tt), 0.f), MW);
            SP += refr; MW -= refr;
            const float tosoil = fmaxf(MW - CWH * SP, 0.f);
            MW -= tosoil;

            // soil bucket (SM > 0 strictly: native log safe)
            const float sw   = fminf(powpos(SM * invFC, beta), 1.f);
            const float rts  = rain + tosoil;
            SM = fmaf(rts, 1.f - sw, SM);
            const float exc = fmaxf(SM - FC, 0.f);
            SM = fminf(SM, FC);
            const float ef = powpos(fminf(SM * invLPFC, 1.f), betaet);
            const float ET = fminf(SM, PETt * ef);
            SM = fmaxf(SM - ET, 1e-5f);
            // Cc<=1, factor<=1 -> product <= SLZ; reference min is redundant
            const float cap = Cc * SLZ * (1.f - fminf(SM * invFC, 1.f));
            SM  = fmaxf(SM + cap, 1e-5f);
            SLZ = fmaxf(SLZ - cap, 1e-5f);

            // groundwater buckets
            SUZ += rts * sw + exc;
            const float perc = fminf(SUZ, PERCp);
            SUZ -= perc;
            const float Q0 = K0 * fmaxf(SUZ - UZL, 0.f);
            SUZ -= Q0;
            const float Q1 = K1 * SUZ;
            SUZ -= Q1;
            SLZ += perc;
            const float gw = fminf(SLZ, gwcap);
            SLZ -= gw;
            const float Q2 = K2 * SLZ;
            SLZ -= Q2;
            const float Qt = Q0 + Q1 + Q2;

            // per-half 15-tap UH ring on OWN Qm (no per-step cross-lane op;
            // flow = ring(Qm0) + ring(Qm1) by linearity, combined at epilogue)
#pragma unroll
            for (int k = 0; k < CH; ++k)
                facc[(j + k) % CH] = fmaf(w[k], Qt, facc[(j + k) % CH]);
            ofl[j]  = facc[j];   // own-half partial flow[t] complete
            facc[j] = 0.f;       // recycle slot for t+15

            Pc = Pn; Tc = Tn; Ec = En; dvc = dvn;
        }
        // epilogue: batched cross-half combine (15 ds_permute, off the chain)
        float prt[CH];
#pragma unroll
        for (int j = 0; j < CH; ++j) prt[j] = __shfl_xor(ofl[j], 32);
        // stores BEFORE next issue() so the next chunk's 14 DMAs stay the
        // newest vmcnt entries (WAIT_VMCNT(14) then allows exactly them)
        if (doStore) {
            float* op = out + (size_t)c * CH * NG + g;
            const int tb = c * CH;
#pragma unroll
            for (int j = 0; j < CH; ++j)
                if (tb + j < TS) op[(size_t)j * NG] = ofl[j] + prt[j];
        }
    };

    // prolog: both buffers' DMAs in flight
    issue(0, xls0, dls0);
    issue(1, xls1, dls1);

    for (int cp = 0; cp < 24; ++cp) {
        const int c0 = 2 * cp;
        WAIT_VMCNT(14);                    // chunk c0 DMAs (+older stores) drained
        chunk(c0, xls0, dls0);
        WAIT_LGKM0;                        // ds_reads/permutes retired (WAR)
        issue(c0 + 2, xls0, dls0);
        WAIT_VMCNT(14);
        chunk(c0 + 1, xls1, dls1);
        WAIT_LGKM0;
        if (cp < 23) issue(c0 + 3, xls1, dls1);
    }
    WAIT_VMCNT(14);                        // chunk-48 DMAs drained
    chunk(48, xls0, dls0);
}

extern "C" void kernel_launch(void* const* d_in, const int* in_sizes, int n_in,
                              void* d_out, int out_size, void* d_ws, size_t ws_size,
                              hipStream_t stream) {
    const float* x_phy = (const float*)d_in[0];
    const float* ac    = (const float*)d_in[1];
    // d_in[2] = elev_all: unused by the reference forward
    const float* pdy   = (const float*)d_in[3];
    const float* pst   = (const float*)d_in[4];
    float* out = (float*)d_out;

    const int grid = (NG + 31) / 32;  // 313 single-wave blocks
    hbv_fused<<<grid, 64, 0, stream>>>(x_phy, ac, pdy, pst, out);
}